// Round 3
// baseline (238.900 us; speedup 1.0000x reference)
//
#include <hip/hip_runtime.h>
#include <hip/hip_bf16.h>
#include <cstdint>
#include <cstddef>

typedef __bf16 bf16;
typedef __bf16 bf16x4 __attribute__((ext_vector_type(4)));
typedef __bf16 bf16x8 __attribute__((ext_vector_type(8)));
typedef float  f32x4  __attribute__((ext_vector_type(4)));

#define DEVINL __device__ __forceinline__

constexpr int   Bc  = 2, Sc = 2048, Hc = 1024, NHc = 16, HDc = 64;
constexpr int   Tc  = Bc * Sc;                 // 4096 tokens
constexpr float L2E = 1.44269504088896340736f;
constexpr float NEG_BIG = -1.0e30f;

typedef __attribute__((address_space(1))) void AS1void;
typedef __attribute__((address_space(3))) void AS3void;

DEVINL void load_lds16(const bf16* g, bf16* l) {
  __builtin_amdgcn_global_load_lds((AS1void*)g, (AS3void*)l, 16, 0, 0);
}

// XOR-swizzle: slot s of row r holds global chunk (s ^ (r & (R-1))) [R9: 41x conflict cut]
// XCD model [R11-validated]: XCD = flat_block_id % 8; within-XCD round-robin
// puts blocks {flat, flat+256, ...} on one CU.

// ---------------------------------------------------------------------------
// Fused fp32->bf16 conversion of all inputs + bias pack, ONE dispatch.
// ---------------------------------------------------------------------------
__global__ __launch_bounds__(256)
void convert_all(const float* __restrict__ hs, const float* __restrict__ Wqkv,
                 const float* __restrict__ Wqa, const float* __restrict__ Wka,
                 const float* __restrict__ Wd, const float* __restrict__ bqa,
                 const float* __restrict__ bka,
                 bf16* __restrict__ hsb, bf16* __restrict__ wqkvb,
                 bf16* __restrict__ wqakab, bf16* __restrict__ wdb,
                 float* __restrict__ bqaka) {
  const int blk = blockIdx.x;
  if (blk >= 5120) {  // bias pack: 2048 floats
    const int i = threadIdx.x * 8;
    const float* src = (i < 1024) ? (bqa + i) : (bka + i - 1024);
    *(f32x4*)(bqaka + i)     = *(const f32x4*)src;
    *(f32x4*)(bqaka + i + 4) = *(const f32x4*)(src + 4);
    return;
  }
  const float* src; bf16* dst; int base;
  if      (blk < 2048) { src = hs;   dst = hsb;                    base = blk; }
  else if (blk < 3584) { src = Wqkv; dst = wqkvb;                  base = blk - 2048; }
  else if (blk < 4096) { src = Wqa;  dst = wqakab;                 base = blk - 3584; }
  else if (blk < 4608) { src = Wka;  dst = wqakab + 1024 * 1024;   base = blk - 4096; }
  else                 { src = Wd;   dst = wdb;                    base = blk - 4608; }
  const int i = (base * 256 + threadIdx.x) * 8;
  f32x4 a = *(const f32x4*)(src + i);
  f32x4 b = *(const f32x4*)(src + i + 4);
  bf16x8 v;
#pragma unroll
  for (int j = 0; j < 4; j++) { v[j] = (bf16)a[j]; v[4 + j] = (bf16)b[j]; }
  *(bf16x8*)(dst + i) = v;
}

// ---------------------------------------------------------------------------
// gemm128: C[M][N] = A[M][K] @ Bw[N][K]^T + bias[N]; 128x128 tile, BK=64,
// XOR-swizzled LDS. min 3 waves/EU (LDS 32 KB -> 3 blocks/CU fits).
// ---------------------------------------------------------------------------
template <typename CT>
__global__ __launch_bounds__(256, 3)
void gemm128(const bf16* __restrict__ A, const bf16* __restrict__ Bw,
             const float* __restrict__ bias, CT* __restrict__ C,
             int M, int N, int K) {
  __shared__ __attribute__((aligned(16))) bf16 As[128 * 64];
  __shared__ __attribute__((aligned(16))) bf16 Bs[128 * 64];

  const int tid = threadIdx.x, wv = tid >> 6, lane = tid & 63;
  const int m0 = blockIdx.y * 128, n0 = blockIdx.x * 128;
  const int col = lane & 15, quad = lane >> 4;
  const int wrow = (wv >> 1) * 64, wcol = (wv & 1) * 64;

  f32x4 acc[4][4];
#pragma unroll
  for (int i = 0; i < 4; i++)
#pragma unroll
    for (int j = 0; j < 4; j++) acc[i][j] = f32x4{0.f, 0.f, 0.f, 0.f};

  const int srow = tid >> 3;
  const int scol = (((tid & 7) ^ (srow & 7)) << 3);
  const bf16* Ag = A  + (size_t)(m0 + srow) * K + scol;
  const bf16* Bg = Bw + (size_t)(n0 + srow) * K + scol;
  const int cs = col & 7;

  for (int k0 = 0; k0 < K; k0 += 64) {
#pragma unroll
    for (int c = 0; c < 4; c++) {
      load_lds16(Ag + (size_t)(c * 32) * K + k0, As + c * 2048 + tid * 8);
      load_lds16(Bg + (size_t)(c * 32) * K + k0, Bs + c * 2048 + tid * 8);
    }
    __syncthreads();
#pragma unroll
    for (int kk = 0; kk < 64; kk += 32) {
      const int so = ((((kk >> 3) + quad) ^ cs) << 3);
      bf16x8 af[4], bfr[4];
#pragma unroll
      for (int i = 0; i < 4; i++)
        af[i] = *(const bf16x8*)(As + (wrow + i * 16 + col) * 64 + so);
#pragma unroll
      for (int j = 0; j < 4; j++)
        bfr[j] = *(const bf16x8*)(Bs + (wcol + j * 16 + col) * 64 + so);
#pragma unroll
      for (int i = 0; i < 4; i++)
#pragma unroll
        for (int j = 0; j < 4; j++)
          acc[i][j] = __builtin_amdgcn_mfma_f32_16x16x32_bf16(af[i], bfr[j], acc[i][j], 0, 0, 0);
    }
    __syncthreads();
  }

#pragma unroll
  for (int j = 0; j < 4; j++) {
    const int c = n0 + wcol + j * 16 + col;
    const float bv = bias[c];
#pragma unroll
    for (int i = 0; i < 4; i++)
#pragma unroll
      for (int r = 0; r < 4; r++) {
        const int rr = m0 + wrow + i * 16 + quad * 4 + r;
        C[(size_t)rr * N + c] = (CT)(acc[i][j][r] + bv);
      }
  }
}

// ---------------------------------------------------------------------------
// gemm6464: 64x64 tile, wave w owns rows 16w..16w+15 x all 64 cols.
// 1024 blocks for the final projection (was grid-starved at 512). LDS 16 KB
// -> 4 blocks/CU at min 4 waves/EU.
// ---------------------------------------------------------------------------
template <typename CT>
__global__ __launch_bounds__(256, 4)
void gemm6464(const bf16* __restrict__ A, const bf16* __restrict__ Bw,
              const float* __restrict__ bias, CT* __restrict__ C,
              int M, int N, int K) {
  __shared__ __attribute__((aligned(16))) bf16 As[64 * 64];
  __shared__ __attribute__((aligned(16))) bf16 Bs[64 * 64];

  const int tid = threadIdx.x, wv = tid >> 6, lane = tid & 63;
  const int m0 = blockIdx.y * 64, n0 = blockIdx.x * 64;
  const int col = lane & 15, quad = lane >> 4;

  f32x4 acc[4];
#pragma unroll
  for (int j = 0; j < 4; j++) acc[j] = f32x4{0.f, 0.f, 0.f, 0.f};

  const int srow = tid >> 3;
  const int scol = (((tid & 7) ^ (srow & 7)) << 3);
  const bf16* Ag = A  + (size_t)(m0 + srow) * K + scol;
  const bf16* Bg = Bw + (size_t)(n0 + srow) * K + scol;
  const int cs = col & 7;

  for (int k0 = 0; k0 < K; k0 += 64) {
#pragma unroll
    for (int c = 0; c < 2; c++) {
      load_lds16(Ag + (size_t)(c * 32) * K + k0, As + c * 2048 + tid * 8);
      load_lds16(Bg + (size_t)(c * 32) * K + k0, Bs + c * 2048 + tid * 8);
    }
    __syncthreads();
#pragma unroll
    for (int kk = 0; kk < 64; kk += 32) {
      const int so = ((((kk >> 3) + quad) ^ cs) << 3);
      bf16x8 af = *(const bf16x8*)(As + (wv * 16 + col) * 64 + so);
#pragma unroll
      for (int j = 0; j < 4; j++) {
        bf16x8 bfr = *(const bf16x8*)(Bs + (j * 16 + col) * 64 + so);
        acc[j] = __builtin_amdgcn_mfma_f32_16x16x32_bf16(af, bfr, acc[j], 0, 0, 0);
      }
    }
    __syncthreads();
  }

#pragma unroll
  for (int j = 0; j < 4; j++) {
    const int c = n0 + j * 16 + col;
    const float bv = bias[c];
#pragma unroll
    for (int r = 0; r < 4; r++) {
      const int rr = m0 + wv * 16 + quad * 4 + r;
      C[(size_t)rr * N + c] = (CT)(acc[j][r] + bv);
    }
  }
}

// ---------------------------------------------------------------------------
// Sliding-window (W=16) attention with FUSED RoPE and FUSED V-transpose.
// ---------------------------------------------------------------------------
__global__ __launch_bounds__(256)
void window_attn(const bf16* __restrict__ qkv, bf16* __restrict__ Ah,
                 bf16* __restrict__ VTg) {
  __shared__ __attribute__((aligned(16))) bf16 Kw[31 * 72];
  __shared__ __attribute__((aligned(16))) bf16 Vw[31 * 72];
  const int g  = blockIdx.x;
  const int st = g & 127;
  const int h  = (g >> 7) & 15;
  const int b  = g >> 11;
  const int s0 = st * 16;
  const int tid = threadIdx.x;

  if ((tid < 124) || (tid >= 128 && tid < 252)) {
    const bool isK = tid < 124;
    const int lt  = isK ? tid : tid - 128;
    const int r   = lt >> 2, off = (lt & 3) << 4;
    int sidx = s0 - 15 + r; if (sidx < 0) sidx = 0;
    const bf16* src = qkv + (size_t)(b * Sc + sidx) * 3072 + (isK ? 1024 : 2048) + h * 64 + off;
    bf16x8 v0 = *(const bf16x8*)src;
    bf16x8 v1 = *(const bf16x8*)(src + 8);
    if (isK && off == 0) {
#pragma unroll
      for (int j = 0; j < 8; j++) {
        const float invf = exp2f(-(float)j * 1.66096404744368128f);
        float sn, csn;
        sincosf((float)sidx * invf, &sn, &csn);
        const float x1 = (float)v0[j], x2 = (float)v1[j];
        v0[j] = (bf16)(x1 * csn - x2 * sn);
        v1[j] = (bf16)(x2 * csn + x1 * sn);
      }
    }
    bf16* dst = (isK ? Kw : Vw) + r * 72 + off;
    *(bf16x8*)dst       = v0;
    *(bf16x8*)(dst + 8) = v1;
  }
  __syncthreads();

  const int wv = tid >> 6, lane = tid & 63;
  const int subq = lane >> 4, lane16 = lane & 15;
  const int s = s0 + wv * 4 + subq;
  const int t = b * Sc + s;
  const int d0 = lane16 * 4;

  float qd[4];
  {
    bf16x4 qv = *(const bf16x4*)(qkv + (size_t)t * 3072 + h * 64 + d0);
#pragma unroll
    for (int j = 0; j < 4; j++) qd[j] = (float)qv[j];
  }
  float pd[4];
#pragma unroll
  for (int j = 0; j < 4; j++) pd[j] = __shfl_xor(qd[j], 2, 64);
  if (lane16 < 4) {
#pragma unroll
    for (int j = 0; j < 4; j++) {
      const int jabs = d0 + j;
      const float invf = exp2f(-(float)(jabs & 7) * 1.66096404744368128f);
      float sn, csn;
      sincosf((float)s * invf, &sn, &csn);
      qd[j] = (jabs < 8) ? (qd[j] * csn - pd[j] * sn) : (qd[j] * csn + pd[j] * sn);
    }
  }

  float sc[16];
#pragma unroll
  for (int w = 0; w < 16; w++) {
    const int idxp = s - 15 + w;
    const int row = idxp - s0 + 15;
    bf16x4 kv = *(const bf16x4*)(Kw + row * 72 + d0);
    float p = qd[0] * (float)kv[0] + qd[1] * (float)kv[1] +
              qd[2] * (float)kv[2] + qd[3] * (float)kv[3];
#pragma unroll
    for (int m = 1; m < 16; m <<= 1) p += __shfl_xor(p, m, 64);
    sc[w] = (idxp < 0) ? NEG_BIG : p * 0.125f;
  }
  float mx = sc[0];
#pragma unroll
  for (int w = 1; w < 16; w++) mx = fmaxf(mx, sc[w]);
  float sum = 0.f;
#pragma unroll
  for (int w = 0; w < 16; w++) { sc[w] = exp2f((sc[w] - mx) * L2E); sum += sc[w]; }
  const float inv = 1.0f / fmaxf(sum, 1e-30f);

  float acc[4] = {0.f, 0.f, 0.f, 0.f};
#pragma unroll
  for (int w = 0; w < 16; w++) {
    const int idxp = s - 15 + w;
    const int row = idxp - s0 + 15;
    bf16x4 vv = *(const bf16x4*)(Vw + row * 72 + d0);
#pragma unroll
    for (int j = 0; j < 4; j++) acc[j] += sc[w] * (float)vv[j];
  }
  bf16x4 ov;
#pragma unroll
  for (int j = 0; j < 4; j++) ov[j] = (bf16)(acc[j] * inv);
  *(bf16x4*)(Ah + (size_t)t * 1024 + h * 64 + d0) = ov;
  bf16* vt = VTg + (((size_t)(b * 16 + h)) * 64 + d0) * 2048 + s;
#pragma unroll
  for (int j = 0; j < 4; j++) vt[(size_t)j * 2048] = ov[j];
}

// ---------------------------------------------------------------------------
// Dense causal flash attention.
//
// R12: T12 in-register softmax (swapped QK^T): mfma(kf, qf) gives
// S^T[key=quad*4+r][q=lane&15]; P->bf16 A-fragment built entirely in
// registers via v_cvt_pk_bf16_f32 + permlane32/16_swap. No P_lds.
// R13: makespan-equalized pairing (nkt(qt)+nkt(31-qt)==17) + double-buffered
// K/VT staging; every block exactly 17 tiles.
//
// R14: KEY-SPLIT 8-WAVE BLOCKS (512 thr). R13 was latency-bound at 2
// waves/SIMD (MfmaUtil 14, VALUBusy 50, occ 16.6%): each wave's tile is one
// serial chain (ds_read->QK->exp->pack->PV) and 2 streams/SIMD can't cover
// it. Wave w = (qw=w>>1, kw=w&1): qw = 16-row q-subtile, kw = 64-key half.
// Per-wave work halves, streams/SIMD double (4). LDS unchanged (64 KB,
// 2 blocks/CU -> 16 waves/CU). New cost: cross-kw reduce of (oacc,lsum) at
// segment end (2x/block) through the DEAD K/VT buffers of the current tile
// (stride-17 f32 layout = conflict-free), 2 extra barriers per segment.
// ---------------------------------------------------------------------------
__global__ __launch_bounds__(512, 4)
void flash_attn(const bf16* __restrict__ Q, const bf16* __restrict__ Kt,
                const bf16* __restrict__ VTg, bf16* __restrict__ O) {
  constexpr int QS = 2048;
  constexpr float SHIFT = 16.0f;
  __shared__ __attribute__((aligned(16))) bf16 K_lds[2][128 * 64];
  __shared__ __attribute__((aligned(16))) bf16 VT_lds[2][64 * 128];

  const int tid = threadIdx.x, wv = tid >> 6, lane = tid & 63;
  const int kw = wv & 1, qw = wv >> 1;  // key-half, q-subtile
  const int bh = blockIdx.x;            // 0..31
  const int y  = blockIdx.y;            // 0..15
  const int qtA = y, qtB = 31 - y;
  const int nA = (qtA + 2) >> 1;        // tiles in segment A; nA + nB == 17
  const int b = bh >> 4, h = bh & 15;
  const int col = lane & 15, quad = lane >> 4;
  const size_t bS = (size_t)b * Sc;
  const int hd = h * 64;

  // staging indices (512 threads; dest = c*4096 + tid*8 for both tiles)
  const int krow = tid >> 3;                       // 0..63 (K row within c-half)
  const int kcol = (((tid & 7) ^ (krow & 7)) << 3);
  const int vrow = tid >> 4;                       // 0..31 (VT row within c-half)
  const int vcol = (((tid & 15) ^ (vrow & 15)) << 3);
  const int cs8 = col & 7;

  // Q fragments for BOTH segments (this wave's q-subtile), named regs.
  bf16x8 qA0, qA1, qB0, qB1;
  {
    const bf16* qpA = Q + (bS + qtA * 64 + qw * 16 + col) * QS + hd + quad * 8;
    const bf16* qpB = Q + (bS + qtB * 64 + qw * 16 + col) * QS + hd + quad * 8;
    qA0 = *(const bf16x8*)qpA;
    qA1 = *(const bf16x8*)(qpA + 32);
    qB0 = *(const bf16x8*)qpB;
    qB1 = *(const bf16x8*)(qpB + 32);
#pragma unroll
    for (int j = 0; j < 8; j++) {
      qA0[j] = (bf16)((float)qA0[j] * 0.125f);
      qA1[j] = (bf16)((float)qA1[j] * 0.125f);
      qB0[j] = (bf16)((float)qB0[j] * 0.125f);
      qB1[j] = (bf16)((float)qB1[j] * 0.125f);
    }
  }

  auto stage = [&](int bufi, int k0) {
#pragma unroll
    for (int c = 0; c < 2; c++) {
      load_lds16(Kt + (bS + k0 + c * 64 + krow) * QS + hd + kcol,
                 K_lds[bufi] + c * 4096 + tid * 8);
      load_lds16(VTg + ((size_t)bh * 64 + c * 32 + vrow) * 2048 + k0 + vcol,
                 VT_lds[bufi] + c * 4096 + tid * 8);
    }
  };

  f32x4 oacc[4];
#pragma unroll
  for (int i = 0; i < 4; i++) oacc[i] = f32x4{0.f, 0.f, 0.f, 0.f};
  float lsum = 0.f;

  stage(0, 0);
  __syncthreads();
  int cur = 0;

  for (int it = 0; it < 17; it++) {
    const int seg  = (it >= nA);
    const int kt   = seg ? (it - nA) : it;
    const int nkt  = seg ? (17 - nA) : nA;
    const int qt   = seg ? qtB : qtA;
    const int k0   = kt * 128;
    const int qbase = qt * 64 + qw * 16;

    // issue NEXT tile's staging before compute (overlaps with this tile)
    if (it + 1 < 17) {
      const int kt2 = (it + 1 >= nA) ? (it + 1 - nA) : (it + 1);
      stage(cur ^ 1, kt2 * 128);
    }

    bf16x8 q0, q1;
    if (seg == 0) { q0 = qA0; q1 = qA1; } else { q0 = qB0; q1 = qB1; }

    const bf16* Kl = K_lds[cur] + kw * 4096;   // this wave's 64-key half
    const bf16* Vl = VT_lds[cur];

    // swapped QK^T: sacc[sub][r] = S^T[key = k0+kw*64+sub*16+quad*4+r][q=qbase+col]
    f32x4 sacc[4];
#pragma unroll
    for (int sub = 0; sub < 4; sub++) {
      f32x4 a = f32x4{0.f, 0.f, 0.f, 0.f};
      {
        const int so = ((quad ^ cs8) << 3);
        bf16x8 kf = *(const bf16x8*)(Kl + (sub * 16 + col) * 64 + so);
        a = __builtin_amdgcn_mfma_f32_16x16x32_bf16(kf, q0, a, 0, 0, 0);
      }
      {
        const int so = (((4 + quad) ^ cs8) << 3);
        bf16x8 kf = *(const bf16x8*)(Kl + (sub * 16 + col) * 64 + so);
        a = __builtin_amdgcn_mfma_f32_16x16x32_bf16(kf, q1, a, 0, 0, 0);
      }
      sacc[sub] = a;
    }
    if (kt == nkt - 1) {
      const int qq = qbase + col;
#pragma unroll
      for (int sub = 0; sub < 4; sub++)
#pragma unroll
        for (int r = 0; r < 4; r++) {
          const int key = k0 + kw * 64 + sub * 16 + quad * 4 + r;
          if (key > qq) sacc[sub][r] = NEG_BIG;
        }
    }
#pragma unroll
    for (int sub = 0; sub < 4; sub++)
#pragma unroll
      for (int r = 0; r < 4; r++) {
        sacc[sub][r] = exp2f(sacc[sub][r] * L2E - SHIFT);
        lsum += sacc[sub][r];
      }

    // PV with in-register P fragment (cvt_pk + permlane32/16 swap pairs).
    // 32-key groups t=0,1 of this wave's half -> V slot base 8*kw + 4*t.
#pragma unroll
    for (int t = 0; t < 2; t++) {
      uint32_t a0, a1, b0, b1;
      asm("v_cvt_pk_bf16_f32 %0, %1, %2"
          : "=v"(a0) : "v"(sacc[2 * t][0]), "v"(sacc[2 * t][1]));
      asm("v_cvt_pk_bf16_f32 %0, %1, %2"
          : "=v"(a1) : "v"(sacc[2 * t][2]), "v"(sacc[2 * t][3]));
      asm("v_cvt_pk_bf16_f32 %0, %1, %2"
          : "=v"(b0) : "v"(sacc[2 * t + 1][0]), "v"(sacc[2 * t + 1][1]));
      asm("v_cvt_pk_bf16_f32 %0, %1, %2"
          : "=v"(b1) : "v"(sacc[2 * t + 1][2]), "v"(sacc[2 * t + 1][3]));
      asm("v_permlane32_swap_b32 %0, %1" : "+v"(a0), "+v"(b0));
      asm("v_permlane16_swap_b32 %0, %1" : "+v"(a0), "+v"(b0));
      asm("v_permlane32_swap_b32 %0, %1" : "+v"(a1), "+v"(b1));
      asm("v_permlane16_swap_b32 %0, %1" : "+v"(a1), "+v"(b1));
      union { uint32_t u[4]; bf16x8 v; } pk;
      pk.u[0] = a0; pk.u[1] = a1; pk.u[2] = b0; pk.u[3] = b1;
      const int vso = (((8 * kw + 4 * t + quad) ^ col) << 3);
#pragma unroll
      for (int nb = 0; nb < 4; nb++) {
        bf16x8 vf = *(const bf16x8*)(Vl + (nb * 16 + col) * 128 + vso);
        oacc[nb] = __builtin_amdgcn_mfma_f32_16x16x32_bf16(pk.v, vf, oacc[nb], 0, 0, 0);
      }
    }

    // segment finalize: cross-kw reduce via dead LDS buffers, write O, reset
    if (kt == nkt - 1) {
      __syncthreads();   // all waves done reading K_lds/VT_lds[cur]
      float* scr = (qw < 2) ? (float*)(&K_lds[cur][0]) + ((qw * 64) + lane) * 17
                            : (float*)(&VT_lds[cur][0]) + (((qw - 2) * 64) + lane) * 17;
      if (kw == 1) {
#pragma unroll
        for (int nb = 0; nb < 4; nb++)
#pragma unroll
          for (int r = 0; r < 4; r++) scr[nb * 4 + r] = oacc[nb][r];
        scr[16] = lsum;
      }
      __syncthreads();
      if (kw == 0) {
#pragma unroll
        for (int nb = 0; nb < 4; nb++)
#pragma unroll
          for (int r = 0; r < 4; r++) oacc[nb][r] += scr[nb * 4 + r];
        float tot = lsum + scr[16];
        tot += __shfl_xor(tot, 16, 64);
        tot += __shfl_xor(tot, 32, 64);
        float lrow[4];
#pragma unroll
        for (int r = 0; r < 4; r++)
          lrow[r] = 1.0f / fmaxf(__shfl(tot, quad * 4 + r, 16), 1e-37f);
#pragma unroll
        for (int nb = 0; nb < 4; nb++)
#pragma unroll
          for (int r = 0; r < 4; r++) {
            const int qq = qbase + quad * 4 + r;
            O[(bS + qq) * 1024 + hd + nb * 16 + col] = (bf16)(oacc[nb][r] * lrow[r]);
          }
      }
#pragma unroll
      for (int i = 0; i < 4; i++) oacc[i] = f32x4{0.f, 0.f, 0.f, 0.f};
      lsum = 0.f;
    }

    __syncthreads();   // drains next-tile staging (vmcnt0) + guards LDS reuse
    cur ^= 1;
  }
}

// ---------------------------------------------------------------------------
extern "C" void kernel_launch(void* const* d_in, const int* in_sizes, int n_in,
                              void* d_out, int out_size, void* d_ws, size_t ws_size,
                              hipStream_t stream) {
  (void)in_sizes; (void)n_in; (void)out_size; (void)ws_size;
  const float* hs   = (const float*)d_in[0];
  const float* Wqkv = (const float*)d_in[1];
  const float* bqkv = (const float*)d_in[2];
  const float* Wqa  = (const float*)d_in[3];
  const float* bqa  = (const float*)d_in[4];
  const float* Wka  = (const float*)d_in[5];
  const float* bka  = (const float*)d_in[6];
  const float* Wd   = (const float*)d_in[7];
  const float* bd   = (const float*)d_in[8];
  float* out = (float*)d_out;

  const size_t TH = (size_t)Tc * Hc;            // 4,194,304
  bf16* dob   = (bf16*)d_out;
  bf16* hsb   = dob;
  bf16* wqkvb = dob + TH;
  bf16* Ah    = dob;
  bf16* VTg   = dob + TH;
  bf16* ws     = (bf16*)d_ws;
  bf16* qkv    = ws;
  bf16* qaka   = ws;
  bf16* oh     = ws + 2 * TH;
  bf16* wqakab = ws + 3 * TH;
  bf16* wdb    = wqakab + 2 * 1024 * 1024;
  float* bqaka = (float*)(wdb + 1024 * 1024);

  convert_all<<<dim3(5121), 256, 0, stream>>>(hs, Wqkv, Wqa, Wka, Wd, bqa, bka,
                                              hsb, wqkvb, wqakab, wdb, bqaka);

  gemm128<bf16><<<dim3(24, 32), 256, 0, stream>>>(hsb, wqkvb, bqkv, qkv, Tc, 3 * Hc, Hc);
  window_attn<<<dim3(Tc * NHc / 16), 256, 0, stream>>>(qkv, Ah, VTg);
  gemm128<bf16><<<dim3(16, 32), 256, 0, stream>>>(Ah, wqakab, bqaka, qaka, Tc, 2 * Hc, Hc);
  // flash: 512 blocks x 512 thr; 8 waves = 4 q-subtiles x 2 key-halves
  flash_attn<<<dim3(Bc * NHc, 16), 512, 0, stream>>>(qaka, qaka + Hc, VTg, oh);
  // final projection: 64x64 tiles, 1024 blocks = 4/CU
  gemm6464<float><<<dim3(16, 64), 256, 0, stream>>>(oh, wdb, bd, out, Tc, Hc, Hc);
}

// Round 4
// 226.687 us; speedup vs baseline: 1.0539x; 1.0539x over previous
//
#include <hip/hip_runtime.h>
#include <hip/hip_bf16.h>
#include <cstdint>
#include <cstddef>

typedef __bf16 bf16;
typedef __bf16 bf16x4 __attribute__((ext_vector_type(4)));
typedef __bf16 bf16x8 __attribute__((ext_vector_type(8)));
typedef float  f32x4  __attribute__((ext_vector_type(4)));

#define DEVINL __device__ __forceinline__

constexpr int   Bc  = 2, Sc = 2048, Hc = 1024, NHc = 16, HDc = 64;
constexpr int   Tc  = Bc * Sc;                 // 4096 tokens
constexpr float L2E = 1.44269504088896340736f;
constexpr float NEG_BIG = -1.0e30f;

typedef __attribute__((address_space(1))) void AS1void;
typedef __attribute__((address_space(3))) void AS3void;

DEVINL void load_lds16(const bf16* g, bf16* l) {
  __builtin_amdgcn_global_load_lds((AS1void*)g, (AS3void*)l, 16, 0, 0);
}

#if __has_builtin(__builtin_amdgcn_exp2f)
DEVINL float fast_exp2(float x) { return __builtin_amdgcn_exp2f(x); }
#else
DEVINL float fast_exp2(float x) { return exp2f(x); }
#endif

// XOR-swizzle: slot s of row r holds global chunk (s ^ (r & (R-1))) [R9: 41x conflict cut]
// XCD model [R11-validated]: XCD = flat_block_id % 8; within-XCD round-robin.

// ---------------------------------------------------------------------------
// Fused fp32->bf16 conversion of all inputs + bias pack, ONE dispatch.
// ---------------------------------------------------------------------------
__global__ __launch_bounds__(256)
void convert_all(const float* __restrict__ hs, const float* __restrict__ Wqkv,
                 const float* __restrict__ Wqa, const float* __restrict__ Wka,
                 const float* __restrict__ Wd, const float* __restrict__ bqa,
                 const float* __restrict__ bka,
                 bf16* __restrict__ hsb, bf16* __restrict__ wqkvb,
                 bf16* __restrict__ wqakab, bf16* __restrict__ wdb,
                 float* __restrict__ bqaka) {
  const int blk = blockIdx.x;
  if (blk >= 5120) {  // bias pack: 2048 floats
    const int i = threadIdx.x * 8;
    const float* src = (i < 1024) ? (bqa + i) : (bka + i - 1024);
    *(f32x4*)(bqaka + i)     = *(const f32x4*)src;
    *(f32x4*)(bqaka + i + 4) = *(const f32x4*)(src + 4);
    return;
  }
  const float* src; bf16* dst; int base;
  if      (blk < 2048) { src = hs;   dst = hsb;                    base = blk; }
  else if (blk < 3584) { src = Wqkv; dst = wqkvb;                  base = blk - 2048; }
  else if (blk < 4096) { src = Wqa;  dst = wqakab;                 base = blk - 3584; }
  else if (blk < 4608) { src = Wka;  dst = wqakab + 1024 * 1024;   base = blk - 4096; }
  else                 { src = Wd;   dst = wdb;                    base = blk - 4608; }
  const int i = (base * 256 + threadIdx.x) * 8;
  f32x4 a = *(const f32x4*)(src + i);
  f32x4 b = *(const f32x4*)(src + i + 4);
  bf16x8 v;
#pragma unroll
  for (int j = 0; j < 4; j++) { v[j] = (bf16)a[j]; v[4 + j] = (bf16)b[j]; }
  *(bf16x8*)(dst + i) = v;
}

// ---------------------------------------------------------------------------
// gemm128: C[M][N] = A[M][K] @ Bw[N][K]^T + bias[N]; 128x128 tile, BK=64,
// XOR-swizzled LDS. min 3 waves/EU (LDS 32 KB -> 3 blocks/CU fits).
// ---------------------------------------------------------------------------
template <typename CT>
__global__ __launch_bounds__(256, 3)
void gemm128(const bf16* __restrict__ A, const bf16* __restrict__ Bw,
             const float* __restrict__ bias, CT* __restrict__ C,
             int M, int N, int K) {
  __shared__ __attribute__((aligned(16))) bf16 As[128 * 64];
  __shared__ __attribute__((aligned(16))) bf16 Bs[128 * 64];

  const int tid = threadIdx.x, wv = tid >> 6, lane = tid & 63;
  const int m0 = blockIdx.y * 128, n0 = blockIdx.x * 128;
  const int col = lane & 15, quad = lane >> 4;
  const int wrow = (wv >> 1) * 64, wcol = (wv & 1) * 64;

  f32x4 acc[4][4];
#pragma unroll
  for (int i = 0; i < 4; i++)
#pragma unroll
    for (int j = 0; j < 4; j++) acc[i][j] = f32x4{0.f, 0.f, 0.f, 0.f};

  const int srow = tid >> 3;
  const int scol = (((tid & 7) ^ (srow & 7)) << 3);
  const bf16* Ag = A  + (size_t)(m0 + srow) * K + scol;
  const bf16* Bg = Bw + (size_t)(n0 + srow) * K + scol;
  const int cs = col & 7;

  for (int k0 = 0; k0 < K; k0 += 64) {
#pragma unroll
    for (int c = 0; c < 4; c++) {
      load_lds16(Ag + (size_t)(c * 32) * K + k0, As + c * 2048 + tid * 8);
      load_lds16(Bg + (size_t)(c * 32) * K + k0, Bs + c * 2048 + tid * 8);
    }
    __syncthreads();
#pragma unroll
    for (int kk = 0; kk < 64; kk += 32) {
      const int so = ((((kk >> 3) + quad) ^ cs) << 3);
      bf16x8 af[4], bfr[4];
#pragma unroll
      for (int i = 0; i < 4; i++)
        af[i] = *(const bf16x8*)(As + (wrow + i * 16 + col) * 64 + so);
#pragma unroll
      for (int j = 0; j < 4; j++)
        bfr[j] = *(const bf16x8*)(Bs + (wcol + j * 16 + col) * 64 + so);
#pragma unroll
      for (int i = 0; i < 4; i++)
#pragma unroll
        for (int j = 0; j < 4; j++)
          acc[i][j] = __builtin_amdgcn_mfma_f32_16x16x32_bf16(af[i], bfr[j], acc[i][j], 0, 0, 0);
    }
    __syncthreads();
  }

#pragma unroll
  for (int j = 0; j < 4; j++) {
    const int c = n0 + wcol + j * 16 + col;
    const float bv = bias[c];
#pragma unroll
    for (int i = 0; i < 4; i++)
#pragma unroll
      for (int r = 0; r < 4; r++) {
        const int rr = m0 + wrow + i * 16 + quad * 4 + r;
        C[(size_t)rr * N + c] = (CT)(acc[i][j][r] + bv);
      }
  }
}

// ---------------------------------------------------------------------------
// gemm6464: 64x64 tile, wave w owns rows 16w..16w+15 x all 64 cols.
// ---------------------------------------------------------------------------
template <typename CT>
__global__ __launch_bounds__(256, 4)
void gemm6464(const bf16* __restrict__ A, const bf16* __restrict__ Bw,
              const float* __restrict__ bias, CT* __restrict__ C,
              int M, int N, int K) {
  __shared__ __attribute__((aligned(16))) bf16 As[64 * 64];
  __shared__ __attribute__((aligned(16))) bf16 Bs[64 * 64];

  const int tid = threadIdx.x, wv = tid >> 6, lane = tid & 63;
  const int m0 = blockIdx.y * 64, n0 = blockIdx.x * 64;
  const int col = lane & 15, quad = lane >> 4;

  f32x4 acc[4];
#pragma unroll
  for (int j = 0; j < 4; j++) acc[j] = f32x4{0.f, 0.f, 0.f, 0.f};

  const int srow = tid >> 3;
  const int scol = (((tid & 7) ^ (srow & 7)) << 3);
  const bf16* Ag = A  + (size_t)(m0 + srow) * K + scol;
  const bf16* Bg = Bw + (size_t)(n0 + srow) * K + scol;
  const int cs = col & 7;

  for (int k0 = 0; k0 < K; k0 += 64) {
#pragma unroll
    for (int c = 0; c < 2; c++) {
      load_lds16(Ag + (size_t)(c * 32) * K + k0, As + c * 2048 + tid * 8);
      load_lds16(Bg + (size_t)(c * 32) * K + k0, Bs + c * 2048 + tid * 8);
    }
    __syncthreads();
#pragma unroll
    for (int kk = 0; kk < 64; kk += 32) {
      const int so = ((((kk >> 3) + quad) ^ cs) << 3);
      bf16x8 af = *(const bf16x8*)(As + (wv * 16 + col) * 64 + so);
#pragma unroll
      for (int j = 0; j < 4; j++) {
        bf16x8 bfr = *(const bf16x8*)(Bs + (j * 16 + col) * 64 + so);
        acc[j] = __builtin_amdgcn_mfma_f32_16x16x32_bf16(af, bfr, acc[j], 0, 0, 0);
      }
    }
    __syncthreads();
  }

#pragma unroll
  for (int j = 0; j < 4; j++) {
    const int c = n0 + j * 16 + col;
    const float bv = bias[c];
#pragma unroll
    for (int r = 0; r < 4; r++) {
      const int rr = m0 + wv * 16 + quad * 4 + r;
      C[(size_t)rr * N + c] = (CT)(acc[j][r] + bv);
    }
  }
}

// ---------------------------------------------------------------------------
// Sliding-window (W=16) attention with FUSED RoPE and FUSED V-transpose.
// ---------------------------------------------------------------------------
__global__ __launch_bounds__(256)
void window_attn(const bf16* __restrict__ qkv, bf16* __restrict__ Ah,
                 bf16* __restrict__ VTg) {
  __shared__ __attribute__((aligned(16))) bf16 Kw[31 * 72];
  __shared__ __attribute__((aligned(16))) bf16 Vw[31 * 72];
  const int g  = blockIdx.x;
  const int st = g & 127;
  const int h  = (g >> 7) & 15;
  const int b  = g >> 11;
  const int s0 = st * 16;
  const int tid = threadIdx.x;

  if ((tid < 124) || (tid >= 128 && tid < 252)) {
    const bool isK = tid < 124;
    const int lt  = isK ? tid : tid - 128;
    const int r   = lt >> 2, off = (lt & 3) << 4;
    int sidx = s0 - 15 + r; if (sidx < 0) sidx = 0;
    const bf16* src = qkv + (size_t)(b * Sc + sidx) * 3072 + (isK ? 1024 : 2048) + h * 64 + off;
    bf16x8 v0 = *(const bf16x8*)src;
    bf16x8 v1 = *(const bf16x8*)(src + 8);
    if (isK && off == 0) {
#pragma unroll
      for (int j = 0; j < 8; j++) {
        const float invf = exp2f(-(float)j * 1.66096404744368128f);
        float sn, csn;
        sincosf((float)sidx * invf, &sn, &csn);
        const float x1 = (float)v0[j], x2 = (float)v1[j];
        v0[j] = (bf16)(x1 * csn - x2 * sn);
        v1[j] = (bf16)(x2 * csn + x1 * sn);
      }
    }
    bf16* dst = (isK ? Kw : Vw) + r * 72 + off;
    *(bf16x8*)dst       = v0;
    *(bf16x8*)(dst + 8) = v1;
  }
  __syncthreads();

  const int wv = tid >> 6, lane = tid & 63;
  const int subq = lane >> 4, lane16 = lane & 15;
  const int s = s0 + wv * 4 + subq;
  const int t = b * Sc + s;
  const int d0 = lane16 * 4;

  float qd[4];
  {
    bf16x4 qv = *(const bf16x4*)(qkv + (size_t)t * 3072 + h * 64 + d0);
#pragma unroll
    for (int j = 0; j < 4; j++) qd[j] = (float)qv[j];
  }
  float pd[4];
#pragma unroll
  for (int j = 0; j < 4; j++) pd[j] = __shfl_xor(qd[j], 2, 64);
  if (lane16 < 4) {
#pragma unroll
    for (int j = 0; j < 4; j++) {
      const int jabs = d0 + j;
      const float invf = exp2f(-(float)(jabs & 7) * 1.66096404744368128f);
      float sn, csn;
      sincosf((float)s * invf, &sn, &csn);
      qd[j] = (jabs < 8) ? (qd[j] * csn - pd[j] * sn) : (qd[j] * csn + pd[j] * sn);
    }
  }

  float sc[16];
#pragma unroll
  for (int w = 0; w < 16; w++) {
    const int idxp = s - 15 + w;
    const int row = idxp - s0 + 15;
    bf16x4 kv = *(const bf16x4*)(Kw + row * 72 + d0);
    float p = qd[0] * (float)kv[0] + qd[1] * (float)kv[1] +
              qd[2] * (float)kv[2] + qd[3] * (float)kv[3];
#pragma unroll
    for (int m = 1; m < 16; m <<= 1) p += __shfl_xor(p, m, 64);
    sc[w] = (idxp < 0) ? NEG_BIG : p * 0.125f;
  }
  float mx = sc[0];
#pragma unroll
  for (int w = 1; w < 16; w++) mx = fmaxf(mx, sc[w]);
  float sum = 0.f;
#pragma unroll
  for (int w = 0; w < 16; w++) { sc[w] = exp2f((sc[w] - mx) * L2E); sum += sc[w]; }
  const float inv = 1.0f / fmaxf(sum, 1e-30f);

  float acc[4] = {0.f, 0.f, 0.f, 0.f};
#pragma unroll
  for (int w = 0; w < 16; w++) {
    const int idxp = s - 15 + w;
    const int row = idxp - s0 + 15;
    bf16x4 vv = *(const bf16x4*)(Vw + row * 72 + d0);
#pragma unroll
    for (int j = 0; j < 4; j++) acc[j] += sc[w] * (float)vv[j];
  }
  bf16x4 ov;
#pragma unroll
  for (int j = 0; j < 4; j++) ov[j] = (bf16)(acc[j] * inv);
  *(bf16x4*)(Ah + (size_t)t * 1024 + h * 64 + d0) = ov;
  bf16* vt = VTg + (((size_t)(b * 16 + h)) * 64 + d0) * 2048 + s;
#pragma unroll
  for (int j = 0; j < 4; j++) vt[(size_t)j * 2048] = ov[j];
}

// ---------------------------------------------------------------------------
// Dense causal flash attention.
//
// R12: T12 in-register softmax (swapped QK^T) + cvt_pk/permlane P fragments.
// R13/R14 lesson: per-tile wall ~6700 cyc invariant under waves/SIMD (2 or 4)
// and co-residency (1 or 2 blocks) => the __syncthreads vmcnt(0) drain
// (double-buffer gives only 1 tile of slack) + heavy VALU body are the walls.
//
// R15 (this round): T3/T4 DEEP PIPELINE + q=128 + VALU DIET.
//  - Triple-buffered 32 KB tiles (96 KB LDS), prefetch depth 2: stage(t+2)
//    issued at tile t => 2 full tiles of slack. Counted s_waitcnt vmcnt(4)
//    (never 0 mid-loop; 20 at the two tiles following a segment-end where 16
//    O-stores sit between stage groups -- vmcnt retires in order, m135),
//    raw s_barrier, ONE barrier/tile, NO __syncthreads.
//  - q=128 rows/block: 256 blocks x 17 tiles (nkt(qt)+nkt(15-qt)==17 for
//    128-row tiles), exactly 1/CU, K-staging reuse x2, half the tile-steps.
//  - VALU diet: fold 0.125*L2E into Q frag; drop SHIFT (softmax ratio is
//    shift-invariant; exp2(NEG_BIG)=0); __builtin_amdgcn_exp2f (1 instr);
//    per-lane staging offsets precomputed, uniform k0 advance; setprio(1)
//    around MFMA clusters (T5).
// ---------------------------------------------------------------------------
__global__ __launch_bounds__(512, 2)
void flash_attn(const bf16* __restrict__ Q, const bf16* __restrict__ Kt,
                const bf16* __restrict__ VTg, bf16* __restrict__ O) {
  constexpr int QS = 2048;
  __shared__ __attribute__((aligned(16))) bf16 K_lds[3][128 * 64];
  __shared__ __attribute__((aligned(16))) bf16 VT_lds[3][64 * 128];

  const int tid = threadIdx.x, wv = tid >> 6, lane = tid & 63;
  const int bh = blockIdx.x;            // 0..31  (XCD = bh % 8)
  const int y  = blockIdx.y;            // 0..7
  const int qtA = y, qtB = 15 - y;      // 128-row q-tile ids
  const int nA = y + 1;                 // tiles in segment A; nA + nB == 17
  const int b = bh >> 4, h = bh & 15;
  const int col = lane & 15, quad = lane >> 4;
  const size_t bS = (size_t)b * Sc;
  const int hd = h * 64;
  const int cs8 = col & 7;

  // staging per-lane offsets (elements), uniform part advanced by k0 only
  const int krow = tid >> 3;                              // 0..63 (+c*64)
  const int kswz = (((tid & 7) ^ (krow & 7)) << 3);
  const int vrow = tid >> 4;                              // 0..31 (+c*32)
  const int vswz = (((tid & 15) ^ (vrow & 15)) << 3);
  const bf16* Kg0 = Kt  + (bS * QS) + (size_t)krow * QS + hd + kswz;
  const bf16* Vg0 = VTg + ((size_t)bh * 64 + vrow) * 2048 + vswz;

  // Q fragments for BOTH segments (this wave's 16-row q-subtile).
  // Scale folds 0.125 (attn scale) * L2E (exp2 base change).
  bf16x8 qA0, qA1, qB0, qB1;
  {
    constexpr float QSC = 0.125f * L2E;
    const bf16* qpA = Q + (bS + qtA * 128 + wv * 16 + col) * QS + hd + quad * 8;
    const bf16* qpB = Q + (bS + qtB * 128 + wv * 16 + col) * QS + hd + quad * 8;
    qA0 = *(const bf16x8*)qpA;
    qA1 = *(const bf16x8*)(qpA + 32);
    qB0 = *(const bf16x8*)qpB;
    qB1 = *(const bf16x8*)(qpB + 32);
#pragma unroll
    for (int j = 0; j < 8; j++) {
      qA0[j] = (bf16)((float)qA0[j] * QSC);
      qA1[j] = (bf16)((float)qA1[j] * QSC);
      qB0[j] = (bf16)((float)qB0[j] * QSC);
      qB1[j] = (bf16)((float)qB1[j] * QSC);
    }
  }

  auto stage = [&](int bufi, int k0) {
    const bf16* kg = Kg0 + (size_t)k0 * QS;
    const bf16* vg = Vg0 + k0;
#pragma unroll
    for (int c = 0; c < 2; c++) {
      load_lds16(kg + (size_t)(c * 64) * QS, K_lds[bufi] + c * 4096 + tid * 8);
      load_lds16(vg + (size_t)(c * 32) * 2048, VT_lds[bufi] + c * 4096 + tid * 8);
    }
  };
  auto k0of = [&](int i) { return ((i >= nA) ? i - nA : i) * 128; };

  f32x4 oacc[4];
#pragma unroll
  for (int i = 0; i < 4; i++) oacc[i] = f32x4{0.f, 0.f, 0.f, 0.f};
  float lsum = 0.f;

  // prologue: 2 tiles in flight
  stage(0, 0);
  stage(1, k0of(1));

  for (int it = 0; it < 17; it++) {
    const int seg  = (it >= nA);
    const int kt   = seg ? (it - nA) : it;
    const int nkt  = seg ? (17 - nA) : nA;
    const int qt   = seg ? qtB : qtA;
    const int k0   = kt * 128;
    const int qbase = qt * 128 + wv * 16;
    const int bufc = it % 3;

    // counted wait: ensure S(it) landed; keep S(it+1) (and issue S(it+2)
    // after the barrier) in flight. 20 at the two tiles after a segment end
    // (16 O-stores between stage groups); 0 only at the very last tile.
    if (it == 16)                      asm volatile("s_waitcnt vmcnt(0)" ::: "memory");
    else if (it == nA || it == nA + 1) asm volatile("s_waitcnt vmcnt(20)" ::: "memory");
    else                               asm volatile("s_waitcnt vmcnt(4)" ::: "memory");
    __builtin_amdgcn_s_barrier();
    __builtin_amdgcn_sched_barrier(0);

    if (it + 2 < 17) stage((it + 2) % 3, k0of(it + 2));

    bf16x8 q0, q1;
    if (seg) { q0 = qB0; q1 = qB1; } else { q0 = qA0; q1 = qA1; }

    const bf16* Kl = K_lds[bufc];
    const bf16* Vl = VT_lds[bufc];

    // swapped QK^T: sacc[sub][r] = S^T[key = k0+sub*16+quad*4+r][q=qbase+col]
    f32x4 sacc[8];
    __builtin_amdgcn_s_setprio(1);
#pragma unroll
    for (int sub = 0; sub < 8; sub++) {
      f32x4 a = f32x4{0.f, 0.f, 0.f, 0.f};
      {
        const int so = ((quad ^ cs8) << 3);
        bf16x8 kf = *(const bf16x8*)(Kl + (sub * 16 + col) * 64 + so);
        a = __builtin_amdgcn_mfma_f32_16x16x32_bf16(kf, q0, a, 0, 0, 0);
      }
      {
        const int so = (((4 + quad) ^ cs8) << 3);
        bf16x8 kf = *(const bf16x8*)(Kl + (sub * 16 + col) * 64 + so);
        a = __builtin_amdgcn_mfma_f32_16x16x32_bf16(kf, q1, a, 0, 0, 0);
      }
      sacc[sub] = a;
    }
    __builtin_amdgcn_s_setprio(0);

    if (kt == nkt - 1) {
      const int qq = qbase + col;
#pragma unroll
      for (int sub = 0; sub < 8; sub++)
#pragma unroll
        for (int r = 0; r < 4; r++) {
          const int key = k0 + sub * 16 + quad * 4 + r;
          if (key > qq) sacc[sub][r] = NEG_BIG;
        }
    }
#pragma unroll
    for (int sub = 0; sub < 8; sub++)
#pragma unroll
      for (int r = 0; r < 4; r++) {
        const float p = fast_exp2(sacc[sub][r]);
        sacc[sub][r] = p;
        lsum += p;
      }

    // PV with in-register P fragment (cvt_pk + permlane32/16 swap pairs).
#pragma unroll
    for (int t = 0; t < 4; t++) {
      uint32_t a0, a1, b0, b1;
      asm("v_cvt_pk_bf16_f32 %0, %1, %2"
          : "=v"(a0) : "v"(sacc[2 * t][0]), "v"(sacc[2 * t][1]));
      asm("v_cvt_pk_bf16_f32 %0, %1, %2"
          : "=v"(a1) : "v"(sacc[2 * t][2]), "v"(sacc[2 * t][3]));
      asm("v_cvt_pk_bf16_f32 %0, %1, %2"
          : "=v"(b0) : "v"(sacc[2 * t + 1][0]), "v"(sacc[2 * t + 1][1]));
      asm("v_cvt_pk_bf16_f32 %0, %1, %2"
          : "=v"(b1) : "v"(sacc[2 * t + 1][2]), "v"(sacc[2 * t + 1][3]));
      asm("v_permlane32_swap_b32 %0, %1" : "+v"(a0), "+v"(b0));
      asm("v_permlane16_swap_b32 %0, %1" : "+v"(a0), "+v"(b0));
      asm("v_permlane32_swap_b32 %0, %1" : "+v"(a1), "+v"(b1));
      asm("v_permlane16_swap_b32 %0, %1" : "+v"(a1), "+v"(b1));
      union { uint32_t u[4]; bf16x8 v; } pk;
      pk.u[0] = a0; pk.u[1] = a1; pk.u[2] = b0; pk.u[3] = b1;
      const int vso = (((4 * t + quad) ^ col) << 3);
      __builtin_amdgcn_s_setprio(1);
#pragma unroll
      for (int nb = 0; nb < 4; nb++) {
        bf16x8 vf = *(const bf16x8*)(Vl + (nb * 16 + col) * 128 + vso);
        oacc[nb] = __builtin_amdgcn_mfma_f32_16x16x32_bf16(pk.v, vf, oacc[nb], 0, 0, 0);
      }
      __builtin_amdgcn_s_setprio(0);
    }

    // segment finalize: reduce denominator (wave-local), write O, reset
    if (kt == nkt - 1) {
      float tot = lsum;
      tot += __shfl_xor(tot, 16, 64);
      tot += __shfl_xor(tot, 32, 64);
      float lrow[4];
#pragma unroll
      for (int r = 0; r < 4; r++)
        lrow[r] = 1.0f / fmaxf(__shfl(tot, quad * 4 + r, 16), 1e-37f);
#pragma unroll
      for (int nb = 0; nb < 4; nb++)
#pragma unroll
        for (int r = 0; r < 4; r++) {
          const int qq = qbase + quad * 4 + r;
          O[(bS + qq) * 1024 + hd + nb * 16 + col] = (bf16)(oacc[nb][r] * lrow[r]);
        }
#pragma unroll
      for (int i = 0; i < 4; i++) oacc[i] = f32x4{0.f, 0.f, 0.f, 0.f};
      lsum = 0.f;
    }
  }
}

// ---------------------------------------------------------------------------
extern "C" void kernel_launch(void* const* d_in, const int* in_sizes, int n_in,
                              void* d_out, int out_size, void* d_ws, size_t ws_size,
                              hipStream_t stream) {
  (void)in_sizes; (void)n_in; (void)out_size; (void)ws_size;
  const float* hs   = (const float*)d_in[0];
  const float* Wqkv = (const float*)d_in[1];
  const float* bqkv = (const float*)d_in[2];
  const float* Wqa  = (const float*)d_in[3];
  const float* bqa  = (const float*)d_in[4];
  const float* Wka  = (const float*)d_in[5];
  const float* bka  = (const float*)d_in[6];
  const float* Wd   = (const float*)d_in[7];
  const float* bd   = (const float*)d_in[8];
  float* out = (float*)d_out;

  const size_t TH = (size_t)Tc * Hc;            // 4,194,304
  bf16* dob   = (bf16*)d_out;
  bf16* hsb   = dob;
  bf16* wqkvb = dob + TH;
  bf16* Ah    = dob;
  bf16* VTg   = dob + TH;
  bf16* ws     = (bf16*)d_ws;
  bf16* qkv    = ws;
  bf16* qaka   = ws;
  bf16* oh     = ws + 2 * TH;
  bf16* wqakab = ws + 3 * TH;
  bf16* wdb    = wqakab + 2 * 1024 * 1024;
  float* bqaka = (float*)(wdb + 1024 * 1024);

  convert_all<<<dim3(5121), 256, 0, stream>>>(hs, Wqkv, Wqa, Wka, Wd, bqa, bka,
                                              hsb, wqkvb, wqakab, wdb, bqaka);

  gemm128<bf16><<<dim3(24, 32), 256, 0, stream>>>(hsb, wqkvb, bqkv, qkv, Tc, 3 * Hc, Hc);
  window_attn<<<dim3(Tc * NHc / 16), 256, 0, stream>>>(qkv, Ah, VTg);
  gemm128<bf16><<<dim3(16, 32), 256, 0, stream>>>(Ah, wqakab, bqaka, qaka, Tc, 2 * Hc, Hc);
  // flash: 256 blocks x 512 thr, q=128/block, 17 tiles each, triple-buffered
  flash_attn<<<dim3(Bc * NHc, 8), 512, 0, stream>>>(qaka, qaka + Hc, VTg, oh);
  // final projection: 64x64 tiles, 1024 blocks = 4/CU
  gemm6464<float><<<dim3(16, 64), 256, 0, stream>>>(oh, wdb, bd, out, Tc, Hc, Hc);
}

// Round 5
// 221.146 us; speedup vs baseline: 1.0803x; 1.0251x over previous
//
#include <hip/hip_runtime.h>
#include <hip/hip_bf16.h>
#include <cstdint>
#include <cstddef>

typedef __bf16 bf16;
typedef __bf16 bf16x4 __attribute__((ext_vector_type(4)));
typedef __bf16 bf16x8 __attribute__((ext_vector_type(8)));
typedef float  f32x4  __attribute__((ext_vector_type(4)));

#define DEVINL __device__ __forceinline__

constexpr int   Bc  = 2, Sc = 2048, Hc = 1024, NHc = 16, HDc = 64;
constexpr int   Tc  = Bc * Sc;                 // 4096 tokens
constexpr float L2E = 1.44269504088896340736f;
constexpr float NEG_BIG = -1.0e30f;
constexpr float INV2PI = 0.15915494309189535f;

typedef __attribute__((address_space(1))) void AS1void;
typedef __attribute__((address_space(3))) void AS3void;

DEVINL void load_lds16(const bf16* g, bf16* l) {
  __builtin_amdgcn_global_load_lds((AS1void*)g, (AS3void*)l, 16, 0, 0);
}

#if __has_builtin(__builtin_amdgcn_exp2f)
DEVINL float fast_exp2(float x) { return __builtin_amdgcn_exp2f(x); }
#else
DEVINL float fast_exp2(float x) { return exp2f(x); }
#endif

// sin/cos of (2*pi*rev) via HW v_sin/v_cos (input = revolutions, fract-reduced).
// Phase err at rev<=330: ulp(330)*2pi ~ 1e-4 rad -- far below bf16 quantum.
#if __has_builtin(__builtin_amdgcn_sinf) && __has_builtin(__builtin_amdgcn_cosf) && __has_builtin(__builtin_amdgcn_fractf)
DEVINL void fast_sincos_rev(float rev, float* sn, float* cs) {
  float r = __builtin_amdgcn_fractf(rev);
  *sn = __builtin_amdgcn_sinf(r);
  *cs = __builtin_amdgcn_cosf(r);
}
#else
DEVINL void fast_sincos_rev(float rev, float* sn, float* cs) {
  sincosf(rev * 6.283185307179586f, sn, cs);
}
#endif

// XOR-swizzle: slot s of row r holds global chunk (s ^ (r & (R-1))) [R9: 41x conflict cut]
// XCD model [R11-validated]: XCD = flat_block_id % 8; within-XCD round-robin.

// ---------------------------------------------------------------------------
// Fused fp32->bf16 conversion of all inputs + bias pack, ONE dispatch.
// ---------------------------------------------------------------------------
__global__ __launch_bounds__(256)
void convert_all(const float* __restrict__ hs, const float* __restrict__ Wqkv,
                 const float* __restrict__ Wqa, const float* __restrict__ Wka,
                 const float* __restrict__ Wd, const float* __restrict__ bqa,
                 const float* __restrict__ bka,
                 bf16* __restrict__ hsb, bf16* __restrict__ wqkvb,
                 bf16* __restrict__ wqakab, bf16* __restrict__ wdb,
                 float* __restrict__ bqaka) {
  const int blk = blockIdx.x;
  if (blk >= 5120) {  // bias pack: 2048 floats
    const int i = threadIdx.x * 8;
    const float* src = (i < 1024) ? (bqa + i) : (bka + i - 1024);
    *(f32x4*)(bqaka + i)     = *(const f32x4*)src;
    *(f32x4*)(bqaka + i + 4) = *(const f32x4*)(src + 4);
    return;
  }
  const float* src; bf16* dst; int base;
  if      (blk < 2048) { src = hs;   dst = hsb;                    base = blk; }
  else if (blk < 3584) { src = Wqkv; dst = wqkvb;                  base = blk - 2048; }
  else if (blk < 4096) { src = Wqa;  dst = wqakab;                 base = blk - 3584; }
  else if (blk < 4608) { src = Wka;  dst = wqakab + 1024 * 1024;   base = blk - 4096; }
  else                 { src = Wd;   dst = wdb;                    base = blk - 4608; }
  const int i = (base * 256 + threadIdx.x) * 8;
  f32x4 a = *(const f32x4*)(src + i);
  f32x4 b = *(const f32x4*)(src + i + 4);
  bf16x8 v;
#pragma unroll
  for (int j = 0; j < 4; j++) { v[j] = (bf16)a[j]; v[4 + j] = (bf16)b[j]; }
  *(bf16x8*)(dst + i) = v;
}

// ---------------------------------------------------------------------------
// gemm128: C[M][N] = A[M][K] @ Bw[N][K]^T + bias[N]; 128x128 tile, BK=64,
// XOR-swizzled LDS. min 3 waves/EU (LDS 32 KB -> 3 blocks/CU fits).
// ---------------------------------------------------------------------------
template <typename CT>
__global__ __launch_bounds__(256, 3)
void gemm128(const bf16* __restrict__ A, const bf16* __restrict__ Bw,
             const float* __restrict__ bias, CT* __restrict__ C,
             int M, int N, int K) {
  __shared__ __attribute__((aligned(16))) bf16 As[128 * 64];
  __shared__ __attribute__((aligned(16))) bf16 Bs[128 * 64];

  const int tid = threadIdx.x, wv = tid >> 6, lane = tid & 63;
  const int m0 = blockIdx.y * 128, n0 = blockIdx.x * 128;
  const int col = lane & 15, quad = lane >> 4;
  const int wrow = (wv >> 1) * 64, wcol = (wv & 1) * 64;

  f32x4 acc[4][4];
#pragma unroll
  for (int i = 0; i < 4; i++)
#pragma unroll
    for (int j = 0; j < 4; j++) acc[i][j] = f32x4{0.f, 0.f, 0.f, 0.f};

  const int srow = tid >> 3;
  const int scol = (((tid & 7) ^ (srow & 7)) << 3);
  const bf16* Ag = A  + (size_t)(m0 + srow) * K + scol;
  const bf16* Bg = Bw + (size_t)(n0 + srow) * K + scol;
  const int cs = col & 7;

  for (int k0 = 0; k0 < K; k0 += 64) {
#pragma unroll
    for (int c = 0; c < 4; c++) {
      load_lds16(Ag + (size_t)(c * 32) * K + k0, As + c * 2048 + tid * 8);
      load_lds16(Bg + (size_t)(c * 32) * K + k0, Bs + c * 2048 + tid * 8);
    }
    __syncthreads();
#pragma unroll
    for (int kk = 0; kk < 64; kk += 32) {
      const int so = ((((kk >> 3) + quad) ^ cs) << 3);
      bf16x8 af[4], bfr[4];
#pragma unroll
      for (int i = 0; i < 4; i++)
        af[i] = *(const bf16x8*)(As + (wrow + i * 16 + col) * 64 + so);
#pragma unroll
      for (int j = 0; j < 4; j++)
        bfr[j] = *(const bf16x8*)(Bs + (wcol + j * 16 + col) * 64 + so);
#pragma unroll
      for (int i = 0; i < 4; i++)
#pragma unroll
        for (int j = 0; j < 4; j++)
          acc[i][j] = __builtin_amdgcn_mfma_f32_16x16x32_bf16(af[i], bfr[j], acc[i][j], 0, 0, 0);
    }
    __syncthreads();
  }

#pragma unroll
  for (int j = 0; j < 4; j++) {
    const int c = n0 + wcol + j * 16 + col;
    const float bv = bias[c];
#pragma unroll
    for (int i = 0; i < 4; i++)
#pragma unroll
      for (int r = 0; r < 4; r++) {
        const int rr = m0 + wrow + i * 16 + quad * 4 + r;
        C[(size_t)rr * N + c] = (CT)(acc[i][j][r] + bv);
      }
  }
}

// ---------------------------------------------------------------------------
// gemm12864: 128x64 tile for the final projection (N=1024 -> 512 blocks =
// 2/CU; 128^2 would give only 256 = grid-starved). Wave (wm=wv>>1, wn=wv&1)
// owns rows 64*wm..+63, cols 32*wn..+31: acc 4x2 frags -> 16 MFMA per wave
// per K-step, 2x gemm6464's MFMA density, 2x per-block work. LDS 24 KB.
// ---------------------------------------------------------------------------
template <typename CT>
__global__ __launch_bounds__(256, 3)
void gemm12864(const bf16* __restrict__ A, const bf16* __restrict__ Bw,
               const float* __restrict__ bias, CT* __restrict__ C,
               int M, int N, int K) {
  __shared__ __attribute__((aligned(16))) bf16 As[128 * 64];
  __shared__ __attribute__((aligned(16))) bf16 Bs[64 * 64];

  const int tid = threadIdx.x, wv = tid >> 6, lane = tid & 63;
  const int m0 = blockIdx.y * 128, n0 = blockIdx.x * 64;
  const int col = lane & 15, quad = lane >> 4;
  const int wm = wv >> 1, wn = wv & 1;

  f32x4 acc[4][2];
#pragma unroll
  for (int i = 0; i < 4; i++)
#pragma unroll
    for (int j = 0; j < 2; j++) acc[i][j] = f32x4{0.f, 0.f, 0.f, 0.f};

  const int srow = tid >> 3;
  const int scol = (((tid & 7) ^ (srow & 7)) << 3);
  const bf16* Ag = A  + (size_t)(m0 + srow) * K + scol;
  const bf16* Bg = Bw + (size_t)(n0 + srow) * K + scol;
  const int cs = col & 7;

  for (int k0 = 0; k0 < K; k0 += 64) {
#pragma unroll
    for (int c = 0; c < 4; c++)
      load_lds16(Ag + (size_t)(c * 32) * K + k0, As + c * 2048 + tid * 8);
#pragma unroll
    for (int c = 0; c < 2; c++)
      load_lds16(Bg + (size_t)(c * 32) * K + k0, Bs + c * 2048 + tid * 8);
    __syncthreads();
#pragma unroll
    for (int kk = 0; kk < 64; kk += 32) {
      const int so = ((((kk >> 3) + quad) ^ cs) << 3);
      bf16x8 af[4], bfr[2];
#pragma unroll
      for (int i = 0; i < 4; i++)
        af[i] = *(const bf16x8*)(As + (wm * 64 + i * 16 + col) * 64 + so);
#pragma unroll
      for (int j = 0; j < 2; j++)
        bfr[j] = *(const bf16x8*)(Bs + (wn * 32 + j * 16 + col) * 64 + so);
#pragma unroll
      for (int i = 0; i < 4; i++)
#pragma unroll
        for (int j = 0; j < 2; j++)
          acc[i][j] = __builtin_amdgcn_mfma_f32_16x16x32_bf16(af[i], bfr[j], acc[i][j], 0, 0, 0);
    }
    __syncthreads();
  }

#pragma unroll
  for (int j = 0; j < 2; j++) {
    const int c = n0 + wn * 32 + j * 16 + col;
    const float bv = bias[c];
#pragma unroll
    for (int i = 0; i < 4; i++)
#pragma unroll
      for (int r = 0; r < 4; r++) {
        const int rr = m0 + wm * 64 + i * 16 + quad * 4 + r;
        C[(size_t)rr * N + c] = (CT)(acc[i][j][r] + bv);
      }
  }
}

// ---------------------------------------------------------------------------
// Sliding-window (W=16) attention with FUSED RoPE and FUSED V-transpose.
// R16: RoPE trig via HW v_sin/v_cos (revolutions + fract reduction) instead
// of OCML sincosf; softmax exp via raw v_exp_f32.
// ---------------------------------------------------------------------------
__global__ __launch_bounds__(256)
void window_attn(const bf16* __restrict__ qkv, bf16* __restrict__ Ah,
                 bf16* __restrict__ VTg) {
  __shared__ __attribute__((aligned(16))) bf16 Kw[31 * 72];
  __shared__ __attribute__((aligned(16))) bf16 Vw[31 * 72];
  const int g  = blockIdx.x;
  const int st = g & 127;
  const int h  = (g >> 7) & 15;
  const int b  = g >> 11;
  const int s0 = st * 16;
  const int tid = threadIdx.x;

  if ((tid < 124) || (tid >= 128 && tid < 252)) {
    const bool isK = tid < 124;
    const int lt  = isK ? tid : tid - 128;
    const int r   = lt >> 2, off = (lt & 3) << 4;
    int sidx = s0 - 15 + r; if (sidx < 0) sidx = 0;
    const bf16* src = qkv + (size_t)(b * Sc + sidx) * 3072 + (isK ? 1024 : 2048) + h * 64 + off;
    bf16x8 v0 = *(const bf16x8*)src;
    bf16x8 v1 = *(const bf16x8*)(src + 8);
    if (isK && off == 0) {
#pragma unroll
      for (int j = 0; j < 8; j++) {
        const float invf_rev = exp2f(-(float)j * 1.66096404744368128f) * INV2PI;
        float sn, csn;
        fast_sincos_rev((float)sidx * invf_rev, &sn, &csn);
        const float x1 = (float)v0[j], x2 = (float)v1[j];
        v0[j] = (bf16)(x1 * csn - x2 * sn);
        v1[j] = (bf16)(x2 * csn + x1 * sn);
      }
    }
    bf16* dst = (isK ? Kw : Vw) + r * 72 + off;
    *(bf16x8*)dst       = v0;
    *(bf16x8*)(dst + 8) = v1;
  }
  __syncthreads();

  const int wv = tid >> 6, lane = tid & 63;
  const int subq = lane >> 4, lane16 = lane & 15;
  const int s = s0 + wv * 4 + subq;
  const int t = b * Sc + s;
  const int d0 = lane16 * 4;

  float qd[4];
  {
    bf16x4 qv = *(const bf16x4*)(qkv + (size_t)t * 3072 + h * 64 + d0);
#pragma unroll
    for (int j = 0; j < 4; j++) qd[j] = (float)qv[j];
  }
  float pd[4];
#pragma unroll
  for (int j = 0; j < 4; j++) pd[j] = __shfl_xor(qd[j], 2, 64);
  if (lane16 < 4) {
#pragma unroll
    for (int j = 0; j < 4; j++) {
      const int jabs = d0 + j;
      const float invf_rev = exp2f(-(float)(jabs & 7) * 1.66096404744368128f) * INV2PI;
      float sn, csn;
      fast_sincos_rev((float)s * invf_rev, &sn, &csn);
      qd[j] = (jabs < 8) ? (qd[j] * csn - pd[j] * sn) : (qd[j] * csn + pd[j] * sn);
    }
  }

  float sc[16];
#pragma unroll
  for (int w = 0; w < 16; w++) {
    const int idxp = s - 15 + w;
    const int row = idxp - s0 + 15;
    bf16x4 kv = *(const bf16x4*)(Kw + row * 72 + d0);
    float p = qd[0] * (float)kv[0] + qd[1] * (float)kv[1] +
              qd[2] * (float)kv[2] + qd[3] * (float)kv[3];
#pragma unroll
    for (int m = 1; m < 16; m <<= 1) p += __shfl_xor(p, m, 64);
    sc[w] = (idxp < 0) ? NEG_BIG : p * 0.125f;
  }
  float mx = sc[0];
#pragma unroll
  for (int w = 1; w < 16; w++) mx = fmaxf(mx, sc[w]);
  float sum = 0.f;
#pragma unroll
  for (int w = 0; w < 16; w++) { sc[w] = fast_exp2((sc[w] - mx) * L2E); sum += sc[w]; }
  const float inv = 1.0f / fmaxf(sum, 1e-30f);

  float acc[4] = {0.f, 0.f, 0.f, 0.f};
#pragma unroll
  for (int w = 0; w < 16; w++) {
    const int idxp = s - 15 + w;
    const int row = idxp - s0 + 15;
    bf16x4 vv = *(const bf16x4*)(Vw + row * 72 + d0);
#pragma unroll
    for (int j = 0; j < 4; j++) acc[j] += sc[w] * (float)vv[j];
  }
  bf16x4 ov;
#pragma unroll
  for (int j = 0; j < 4; j++) ov[j] = (bf16)(acc[j] * inv);
  *(bf16x4*)(Ah + (size_t)t * 1024 + h * 64 + d0) = ov;
  bf16* vt = VTg + (((size_t)(b * 16 + h)) * 64 + d0) * 2048 + s;
#pragma unroll
  for (int j = 0; j < 4; j++) vt[(size_t)j * 2048] = ov[j];
}

// ---------------------------------------------------------------------------
// Dense causal flash attention.
//
// R12: T12 in-register softmax (swapped QK^T) + cvt_pk/permlane P fragments.
// R13/R14 lesson: per-tile wall ~6700 cyc invariant under waves/SIMD (2 or 4)
// and co-residency (1 or 2 blocks) => the __syncthreads vmcnt(0) drain
// (double-buffer gives only 1 tile of slack) + heavy VALU body are the walls.
//
// R15 (validated: flash dropped out of top-5, ~47->~35 us): T3/T4 deep
// pipeline -- triple-buffered 32 KB tiles, prefetch depth 2, counted
// s_waitcnt vmcnt (never 0 mid-loop), raw s_barrier, ONE barrier/tile;
// q=128 rows/block (256 blocks x 17 tiles, makespan-balanced); VALU diet
// (folded QSC, no SHIFT, raw v_exp, setprio around MFMA).
// ---------------------------------------------------------------------------
__global__ __launch_bounds__(512, 2)
void flash_attn(const bf16* __restrict__ Q, const bf16* __restrict__ Kt,
                const bf16* __restrict__ VTg, bf16* __restrict__ O) {
  constexpr int QS = 2048;
  __shared__ __attribute__((aligned(16))) bf16 K_lds[3][128 * 64];
  __shared__ __attribute__((aligned(16))) bf16 VT_lds[3][64 * 128];

  const int tid = threadIdx.x, wv = tid >> 6, lane = tid & 63;
  const int bh = blockIdx.x;            // 0..31  (XCD = bh % 8)
  const int y  = blockIdx.y;            // 0..7
  const int qtA = y, qtB = 15 - y;      // 128-row q-tile ids
  const int nA = y + 1;                 // tiles in segment A; nA + nB == 17
  const int b = bh >> 4, h = bh & 15;
  const int col = lane & 15, quad = lane >> 4;
  const size_t bS = (size_t)b * Sc;
  const int hd = h * 64;
  const int cs8 = col & 7;

  // staging per-lane offsets (elements), uniform part advanced by k0 only
  const int krow = tid >> 3;                              // 0..63 (+c*64)
  const int kswz = (((tid & 7) ^ (krow & 7)) << 3);
  const int vrow = tid >> 4;                              // 0..31 (+c*32)
  const int vswz = (((tid & 15) ^ (vrow & 15)) << 3);
  const bf16* Kg0 = Kt  + (bS * QS) + (size_t)krow * QS + hd + kswz;
  const bf16* Vg0 = VTg + ((size_t)bh * 64 + vrow) * 2048 + vswz;

  // Q fragments for BOTH segments (this wave's 16-row q-subtile).
  // Scale folds 0.125 (attn scale) * L2E (exp2 base change).
  bf16x8 qA0, qA1, qB0, qB1;
  {
    constexpr float QSC = 0.125f * L2E;
    const bf16* qpA = Q + (bS + qtA * 128 + wv * 16 + col) * QS + hd + quad * 8;
    const bf16* qpB = Q + (bS + qtB * 128 + wv * 16 + col) * QS + hd + quad * 8;
    qA0 = *(const bf16x8*)qpA;
    qA1 = *(const bf16x8*)(qpA + 32);
    qB0 = *(const bf16x8*)qpB;
    qB1 = *(const bf16x8*)(qpB + 32);
#pragma unroll
    for (int j = 0; j < 8; j++) {
      qA0[j] = (bf16)((float)qA0[j] * QSC);
      qA1[j] = (bf16)((float)qA1[j] * QSC);
      qB0[j] = (bf16)((float)qB0[j] * QSC);
      qB1[j] = (bf16)((float)qB1[j] * QSC);
    }
  }

  auto stage = [&](int bufi, int k0) {
    const bf16* kg = Kg0 + (size_t)k0 * QS;
    const bf16* vg = Vg0 + k0;
#pragma unroll
    for (int c = 0; c < 2; c++) {
      load_lds16(kg + (size_t)(c * 64) * QS, K_lds[bufi] + c * 4096 + tid * 8);
      load_lds16(vg + (size_t)(c * 32) * 2048, VT_lds[bufi] + c * 4096 + tid * 8);
    }
  };
  auto k0of = [&](int i) { return ((i >= nA) ? i - nA : i) * 128; };

  f32x4 oacc[4];
#pragma unroll
  for (int i = 0; i < 4; i++) oacc[i] = f32x4{0.f, 0.f, 0.f, 0.f};
  float lsum = 0.f;

  // prologue: 2 tiles in flight
  stage(0, 0);
  stage(1, k0of(1));

  for (int it = 0; it < 17; it++) {
    const int seg  = (it >= nA);
    const int kt   = seg ? (it - nA) : it;
    const int nkt  = seg ? (17 - nA) : nA;
    const int qt   = seg ? qtB : qtA;
    const int k0   = kt * 128;
    const int qbase = qt * 128 + wv * 16;
    const int bufc = it % 3;

    // counted wait: ensure S(it) landed; keep S(it+1) (and issue S(it+2)
    // after the barrier) in flight. 20 at the two tiles after a segment end
    // (16 O-stores between stage groups); 0 only at the very last tile.
    if (it == 16)                      asm volatile("s_waitcnt vmcnt(0)" ::: "memory");
    else if (it == nA || it == nA + 1) asm volatile("s_waitcnt vmcnt(20)" ::: "memory");
    else                               asm volatile("s_waitcnt vmcnt(4)" ::: "memory");
    __builtin_amdgcn_s_barrier();
    __builtin_amdgcn_sched_barrier(0);

    if (it + 2 < 17) stage((it + 2) % 3, k0of(it + 2));

    bf16x8 q0, q1;
    if (seg) { q0 = qB0; q1 = qB1; } else { q0 = qA0; q1 = qA1; }

    const bf16* Kl = K_lds[bufc];
    const bf16* Vl = VT_lds[bufc];

    // swapped QK^T: sacc[sub][r] = S^T[key = k0+sub*16+quad*4+r][q=qbase+col]
    f32x4 sacc[8];
    __builtin_amdgcn_s_setprio(1);
#pragma unroll
    for (int sub = 0; sub < 8; sub++) {
      f32x4 a = f32x4{0.f, 0.f, 0.f, 0.f};
      {
        const int so = ((quad ^ cs8) << 3);
        bf16x8 kf = *(const bf16x8*)(Kl + (sub * 16 + col) * 64 + so);
        a = __builtin_amdgcn_mfma_f32_16x16x32_bf16(kf, q0, a, 0, 0, 0);
      }
      {
        const int so = (((4 + quad) ^ cs8) << 3);
        bf16x8 kf = *(const bf16x8*)(Kl + (sub * 16 + col) * 64 + so);
        a = __builtin_amdgcn_mfma_f32_16x16x32_bf16(kf, q1, a, 0, 0, 0);
      }
      sacc[sub] = a;
    }
    __builtin_amdgcn_s_setprio(0);

    if (kt == nkt - 1) {
      const int qq = qbase + col;
#pragma unroll
      for (int sub = 0; sub < 8; sub++)
#pragma unroll
        for (int r = 0; r < 4; r++) {
          const int key = k0 + sub * 16 + quad * 4 + r;
          if (key > qq) sacc[sub][r] = NEG_BIG;
        }
    }
#pragma unroll
    for (int sub = 0; sub < 8; sub++)
#pragma unroll
      for (int r = 0; r < 4; r++) {
        const float p = fast_exp2(sacc[sub][r]);
        sacc[sub][r] = p;
        lsum += p;
      }

    // PV with in-register P fragment (cvt_pk + permlane32/16 swap pairs).
#pragma unroll
    for (int t = 0; t < 4; t++) {
      uint32_t a0, a1, b0, b1;
      asm("v_cvt_pk_bf16_f32 %0, %1, %2"
          : "=v"(a0) : "v"(sacc[2 * t][0]), "v"(sacc[2 * t][1]));
      asm("v_cvt_pk_bf16_f32 %0, %1, %2"
          : "=v"(a1) : "v"(sacc[2 * t][2]), "v"(sacc[2 * t][3]));
      asm("v_cvt_pk_bf16_f32 %0, %1, %2"
          : "=v"(b0) : "v"(sacc[2 * t + 1][0]), "v"(sacc[2 * t + 1][1]));
      asm("v_cvt_pk_bf16_f32 %0, %1, %2"
          : "=v"(b1) : "v"(sacc[2 * t + 1][2]), "v"(sacc[2 * t + 1][3]));
      asm("v_permlane32_swap_b32 %0, %1" : "+v"(a0), "+v"(b0));
      asm("v_permlane16_swap_b32 %0, %1" : "+v"(a0), "+v"(b0));
      asm("v_permlane32_swap_b32 %0, %1" : "+v"(a1), "+v"(b1));
      asm("v_permlane16_swap_b32 %0, %1" : "+v"(a1), "+v"(b1));
      union { uint32_t u[4]; bf16x8 v; } pk;
      pk.u[0] = a0; pk.u[1] = a1; pk.u[2] = b0; pk.u[3] = b1;
      const int vso = (((4 * t + quad) ^ col) << 3);
      __builtin_amdgcn_s_setprio(1);
#pragma unroll
      for (int nb = 0; nb < 4; nb++) {
        bf16x8 vf = *(const bf16x8*)(Vl + (nb * 16 + col) * 128 + vso);
        oacc[nb] = __builtin_amdgcn_mfma_f32_16x16x32_bf16(pk.v, vf, oacc[nb], 0, 0, 0);
      }
      __builtin_amdgcn_s_setprio(0);
    }

    // segment finalize: reduce denominator (wave-local), write O, reset
    if (kt == nkt - 1) {
      float tot = lsum;
      tot += __shfl_xor(tot, 16, 64);
      tot += __shfl_xor(tot, 32, 64);
      float lrow[4];
#pragma unroll
      for (int r = 0; r < 4; r++)
        lrow[r] = 1.0f / fmaxf(__shfl(tot, quad * 4 + r, 16), 1e-37f);
#pragma unroll
      for (int nb = 0; nb < 4; nb++)
#pragma unroll
        for (int r = 0; r < 4; r++) {
          const int qq = qbase + quad * 4 + r;
          O[(bS + qq) * 1024 + hd + nb * 16 + col] = (bf16)(oacc[nb][r] * lrow[r]);
        }
#pragma unroll
      for (int i = 0; i < 4; i++) oacc[i] = f32x4{0.f, 0.f, 0.f, 0.f};
      lsum = 0.f;
    }
  }
}

// ---------------------------------------------------------------------------
extern "C" void kernel_launch(void* const* d_in, const int* in_sizes, int n_in,
                              void* d_out, int out_size, void* d_ws, size_t ws_size,
                              hipStream_t stream) {
  (void)in_sizes; (void)n_in; (void)out_size; (void)ws_size;
  const float* hs   = (const float*)d_in[0];
  const float* Wqkv = (const float*)d_in[1];
  const float* bqkv = (const float*)d_in[2];
  const float* Wqa  = (const float*)d_in[3];
  const float* bqa  = (const float*)d_in[4];
  const float* Wka  = (const float*)d_in[5];
  const float* bka  = (const float*)d_in[6];
  const float* Wd   = (const float*)d_in[7];
  const float* bd   = (const float*)d_in[8];
  float* out = (float*)d_out;

  const size_t TH = (size_t)Tc * Hc;            // 4,194,304
  bf16* dob   = (bf16*)d_out;
  bf16* hsb   = dob;
  bf16* wqkvb = dob + TH;
  bf16* Ah    = dob;
  bf16* VTg   = dob + TH;
  bf16* ws     = (bf16*)d_ws;
  bf16* qkv    = ws;
  bf16* qaka   = ws;
  bf16* oh     = ws + 2 * TH;
  bf16* wqakab = ws + 3 * TH;
  bf16* wdb    = wqakab + 2 * 1024 * 1024;
  float* bqaka = (float*)(wdb + 1024 * 1024);

  convert_all<<<dim3(5121), 256, 0, stream>>>(hs, Wqkv, Wqa, Wka, Wd, bqa, bka,
                                              hsb, wqkvb, wqakab, wdb, bqaka);

  gemm128<bf16><<<dim3(24, 32), 256, 0, stream>>>(hsb, wqkvb, bqkv, qkv, Tc, 3 * Hc, Hc);
  window_attn<<<dim3(Tc * NHc / 16), 256, 0, stream>>>(qkv, Ah, VTg);
  gemm128<bf16><<<dim3(16, 32), 256, 0, stream>>>(Ah, wqakab, bqaka, qaka, Tc, 2 * Hc, Hc);
  // flash: 256 blocks x 512 thr, q=128/block, 17 tiles each, triple-buffered
  flash_attn<<<dim3(Bc * NHc, 8), 512, 0, stream>>>(qaka, qaka + Hc, VTg, oh);
  // final projection: 128x64 tiles, 512 blocks = 2/CU (128^2 would be 256=1/CU)
  gemm12864<float><<<dim3(16, 32), 256, 0, stream>>>(oh, wdb, bd, out, Tc, Hc, Hc);
}